// Round 7
// baseline (492.243 us; speedup 1.0000x reference)
//
#include <hip/hip_runtime.h>

#define Bn 4
#define Hn 16
#define Tn 1024
#define Dn 64
#define N4 (Bn*Hn*Tn*Dn)   // 4,194,304 elements per projected tensor
#define TD (Tn*Dn)

typedef __attribute__((ext_vector_type(8))) short bf16x8;
typedef __attribute__((ext_vector_type(4))) float f32x4;

// LAMBDA_INIT = 0.8 - 0.6*exp(-0.3*12)
__device__ __constant__ float LAMBDA_INIT_F = 0.78360576653162445f;

__device__ inline unsigned short bf16_rne(float x) {
    unsigned u = __float_as_uint(x);
    unsigned r = (u + 0x7FFFu + ((u >> 16) & 1u)) >> 16;
    return (unsigned short)r;
}
__device__ inline float bf16_to_f(unsigned short h) {
    return __uint_as_float(((unsigned)h) << 16);
}

// ---------------------------------------------------------------------------
// K0: lambda_full
// ---------------------------------------------------------------------------
__global__ void k_lambda(const float* __restrict__ lq1, const float* __restrict__ lk1,
                         const float* __restrict__ lq2, const float* __restrict__ lk2,
                         float* __restrict__ lam_out) {
    int l = threadIdx.x;  // 64 threads
    float p1 = lq1[l] * lk1[l];
    float p2 = lq2[l] * lk2[l];
    #pragma unroll
    for (int m = 1; m < 64; m <<= 1) {
        p1 += __shfl_xor(p1, m);
        p2 += __shfl_xor(p2, m);
    }
    if (l == 0) lam_out[0] = expf(p1) - expf(p2) + LAMBDA_INIT_F;
}

// ---------------------------------------------------------------------------
// K1: all 4 projections in one launch. idx = bx&3 selects (src, W, dst).
// Also emits bf16 hi/lo split tensors for the MFMA main kernel.
// grid 4096, 256 threads, 64 rows x 64 cols per block.
// ---------------------------------------------------------------------------
__global__ __launch_bounds__(256) void k_proj4(
    const float* __restrict__ q, const float* __restrict__ k,
    const float* __restrict__ W1q, const float* __restrict__ W1k,
    const float* __restrict__ W2q, const float* __restrict__ W2k,
    float* __restrict__ qf1, float* __restrict__ kf1,
    float* __restrict__ qf2, float* __restrict__ kf2,
    unsigned short* __restrict__ qh1, unsigned short* __restrict__ ql1,
    unsigned short* __restrict__ kh1, unsigned short* __restrict__ kl1,
    unsigned short* __restrict__ qh2, unsigned short* __restrict__ ql2,
    unsigned short* __restrict__ kh2, unsigned short* __restrict__ kl2) {

    __shared__ float Qs[64][68];   // [row][d]
    __shared__ float Wt[64][68];   // [e][d]

    int t  = threadIdx.x;
    int bx = blockIdx.x;
    int idx  = bx & 3;
    int tile = bx >> 2;
    int bh = tile >> 4;
    int r0 = (tile & 15) * 64;
    int h  = bh & (Hn - 1);

    const float* src = (idx & 1) ? k : q;
    const float* W = (idx == 0) ? W1q : (idx == 1) ? W1k : (idx == 2) ? W2q : W2k;
    float* dst = (idx == 0) ? qf1 : (idx == 1) ? kf1 : (idx == 2) ? qf2 : kf2;
    unsigned short* dsth = (idx == 0) ? qh1 : (idx == 1) ? kh1 : (idx == 2) ? qh2 : kh2;
    unsigned short* dstl = (idx == 0) ? ql1 : (idx == 1) ? kl1 : (idx == 2) ? ql2 : kl2;

    const float* sbase = src + (size_t)bh * TD + (size_t)r0 * Dn;
    const float* wbase = W + (size_t)h * Dn * Dn;

    #pragma unroll
    for (int it = 0; it < 4; ++it) {
        int f4 = it * 256 + t;           // 0..1023
        int r  = f4 >> 4;
        int d0 = (f4 & 15) << 2;
        float4 v = *(const float4*)&sbase[(size_t)r * Dn + d0];
        *(float4*)&Qs[r][d0] = v;
        float4 w = *(const float4*)&wbase[(size_t)r * Dn + d0]; // r==d, d0==e0
        Wt[d0 + 0][r] = w.x; Wt[d0 + 1][r] = w.y;
        Wt[d0 + 2][r] = w.z; Wt[d0 + 3][r] = w.w;
    }
    __syncthreads();

    int tx = t & 15, ty = t >> 4;
    float acc[4][4];
    #pragma unroll
    for (int i = 0; i < 4; ++i)
        #pragma unroll
        for (int j = 0; j < 4; ++j) acc[i][j] = 0.f;

    #pragma unroll
    for (int d0 = 0; d0 < 64; d0 += 4) {
        float qa[4][4], wb[4][4];
        #pragma unroll
        for (int i = 0; i < 4; ++i) {
            float4 v = *(const float4*)&Qs[4 * ty + i][d0];
            qa[i][0] = v.x; qa[i][1] = v.y; qa[i][2] = v.z; qa[i][3] = v.w;
        }
        #pragma unroll
        for (int j = 0; j < 4; ++j) {
            float4 v = *(const float4*)&Wt[4 * tx + j][d0];
            wb[j][0] = v.x; wb[j][1] = v.y; wb[j][2] = v.z; wb[j][3] = v.w;
        }
        #pragma unroll
        for (int i = 0; i < 4; ++i)
            #pragma unroll
            for (int j = 0; j < 4; ++j)
                #pragma unroll
                for (int p = 0; p < 4; ++p)
                    acc[i][j] = fmaf(qa[i][p], wb[j][p], acc[i][j]);
    }

    float* dbase = dst + (size_t)bh * TD + (size_t)r0 * Dn;
    unsigned short* hbase = dsth + (size_t)bh * TD + (size_t)r0 * Dn;
    unsigned short* lbase = dstl + (size_t)bh * TD + (size_t)r0 * Dn;
    #pragma unroll
    for (int i = 0; i < 4; ++i) {
        size_t off = (size_t)(4 * ty + i) * Dn + 4 * tx;
        float4 o = make_float4(acc[i][0], acc[i][1], acc[i][2], acc[i][3]);
        *(float4*)&dbase[off] = o;
        ushort4 hv, lv;
        hv.x = bf16_rne(o.x); lv.x = bf16_rne(o.x - bf16_to_f(hv.x));
        hv.y = bf16_rne(o.y); lv.y = bf16_rne(o.y - bf16_to_f(hv.y));
        hv.z = bf16_rne(o.z); lv.z = bf16_rne(o.z - bf16_to_f(hv.z));
        hv.w = bf16_rne(o.w); lv.w = bf16_rne(o.w - bf16_to_f(hv.w));
        *(ushort4*)&hbase[off] = hv;
        *(ushort4*)&lbase[off] = lv;
    }
}

// ---------------------------------------------------------------------------
// K2: 128-row block sums of kf (fp32)
// ---------------------------------------------------------------------------
__global__ void k_blocksum(const float* __restrict__ kf1, const float* __restrict__ kf2,
                           float* __restrict__ bs) {
    __shared__ float red[4][64];
    int t  = threadIdx.x;
    int bx = blockIdx.x;
    int j  = bx & 7;
    int br = (bx >> 3) & 1;
    int bh = bx >> 4;
    const float* kf = (br ? kf2 : kf1) + (size_t)bh * TD + (size_t)j * 128 * Dn;
    int d = t & 63, rg = t >> 6;
    float p = 0.f;
    #pragma unroll 4
    for (int r = 0; r < 32; ++r) p += kf[(size_t)(rg * 32 + r) * Dn + d];
    red[rg][d] = p;
    __syncthreads();
    if (rg == 0)
        bs[(((size_t)bh * 2 + br) * 8 + j) * 64 + d] =
            red[0][d] + red[1][d] + red[2][d] + red[3][d];
}

// ---------------------------------------------------------------------------
// K3: exclusive prefix over the 8 block sums -> kc
// ---------------------------------------------------------------------------
__global__ void k_prefix(const float* __restrict__ bs, float* __restrict__ kc) {
    int bx = blockIdx.x;
    int br = bx & 1, bh = bx >> 1;
    int d = threadIdx.x;
    float run = 0.f;
    for (int j = 0; j < 8; ++j) {
        size_t idx = (((size_t)bh * 2 + br) * 8 + j) * 64 + d;
        kc[idx] = run;
        run += bs[idx];
    }
}

// ---------------------------------------------------------------------------
// K_s2: inv_s[bh,br,row] = 1 / ( qf[row] . Pref[min(row+1,1023)] ), fp32.
// One block per (bh,br,chunk of 128 rows); kf chunk staged in LDS; 4 waves
// each serial-walk 32 rows (seeded by intra-chunk wave sums).
// ---------------------------------------------------------------------------
__global__ __launch_bounds__(256) void k_s2(
    const float* __restrict__ qf1, const float* __restrict__ kf1,
    const float* __restrict__ qf2, const float* __restrict__ kf2,
    const float* __restrict__ kc,  float* __restrict__ inv_out) {

    __shared__ float kfl[128][64];
    __shared__ float wsum[4][64];

    int bx = blockIdx.x;            // 1024 = bh(64) x br(2) x j(8)
    int j = bx & 7, br = (bx >> 3) & 1, bh = bx >> 4;
    int t = threadIdx.x;
    int g = t >> 6, d = t & 63;
    int R0 = j * 128;

    const float* qf = (br ? qf2 : qf1) + (size_t)bh * TD;
    const float* kf = (br ? kf2 : kf1) + (size_t)bh * TD;

    #pragma unroll
    for (int it = 0; it < 8; ++it) {
        int f4 = it * 256 + t;       // 0..2047 float4s
        int r = f4 >> 4, c4 = (f4 & 15) << 2;
        *(float4*)&kfl[r][c4] = *(const float4*)&kf[(size_t)(R0 + r) * Dn + c4];
    }
    __syncthreads();

    float ps = 0.f;
    #pragma unroll 8
    for (int r = 0; r < 32; ++r) ps += kfl[g * 32 + r][d];
    wsum[g][d] = ps;
    __syncthreads();

    float run = kc[(((size_t)bh * 2 + br) * 8 + j) * 64 + d];
    #pragma unroll
    for (int g2 = 0; g2 < 3; ++g2) if (g2 < g) run += wsum[g2][d];

    float* inv = inv_out + ((size_t)bh * 2 + br) * Tn;

    #pragma unroll 4
    for (int s = 0; s < 32; ++s) {
        int a = g * 32 + s;
        run += kfl[a][d];            // run = Pref[R0 + a]
        int rr = R0 + a - 1;         // row whose denominator this is
        if (rr >= 0) {
            float dv = qf[(size_t)rr * Dn + d] * run;
            #pragma unroll
            for (int m = 1; m < 64; m <<= 1) dv += __shfl_xor(dv, m);
            if (d == 0) inv[rr] = 1.0f / dv;
        }
    }
    if (j == 7 && g == 3) {          // row 1023: Pref clamps at 1023
        float dv = qf[(size_t)1023 * Dn + d] * run;
        #pragma unroll
        for (int m = 1; m < 64; m <<= 1) dv += __shfl_xor(dv, m);
        if (d == 0) inv[1023] = 1.0f / dv;
    }
}

// ---------------------------------------------------------------------------
// K_tile (MFMA): one 128x128 tile per 512-thread block (8 waves, 32x64 each).
// Numerator via 3-term bf16 split (hh+hl+lh) with mfma_f32_16x16x32_bf16.
// Epilogue: per 32-row stripe, owning waves write masked+normalized acc to
// LDS (reusing the B buffers), then all threads store float4-coalesced.
// grid 4096 = bh(64) x rt(8) x c(8), XCD-chunk swizzled.
// ---------------------------------------------------------------------------
__global__ __launch_bounds__(512, 4) void k_tile(
    const unsigned short* __restrict__ qh1, const unsigned short* __restrict__ ql1,
    const unsigned short* __restrict__ qh2, const unsigned short* __restrict__ ql2,
    const unsigned short* __restrict__ kh1, const unsigned short* __restrict__ kl1,
    const unsigned short* __restrict__ kh2, const unsigned short* __restrict__ kl2,
    const float* __restrict__ qf1, const float* __restrict__ qf2,
    const float* __restrict__ kf1, const float* __restrict__ kf2,
    const float* __restrict__ inv_g, const float* __restrict__ lamp,
    float* __restrict__ out) {

    // raw LDS: B-staging (2 x 10240B) during compute, C-stripe (32x132 f32,
    // 16896B) during epilogue. Aliased — B is dead once accs are in regs.
    __shared__ __align__(16) char raw[20480];
    unsigned short* Bhs = (unsigned short*)raw;          // [128][40]
    unsigned short* Bls = Bhs + 128 * 40;                // [128][40]
    float (*Cst)[132] = (float(*)[132])raw;              // [32][132]
    __shared__ float inv_lds[2][128];
    __shared__ float e_sh[2];

    int t  = threadIdx.x;
    int vid = (blockIdx.x & 7) * 512 + (blockIdx.x >> 3);   // XCD-chunk swizzle
    int bh = vid >> 6;
    int tile = vid & 63;
    int rt = tile >> 3, c = tile & 7;
    int r0 = rt * 128, cb = c * 128;

    const float lam = lamp[0];
    const size_t bb = (size_t)bh * TD;

    // ---------------- fill role ----------------
    if (c > rt) {
        float ev = 0.f;
        if (c == rt + 1) {
            if (t < 128) {
                int br = t >> 6, d = t & 63;
                const float* qp = (br ? qf2 : qf1) + bb;
                const float* kp = (br ? kf2 : kf1) + bb;
                float p = qp[(size_t)(r0 + 127) * Dn + d] * kp[(size_t)cb * Dn + d];
                #pragma unroll
                for (int m = 1; m < 64; m <<= 1) p += __shfl_xor(p, m);
                if (d == 0) e_sh[br] = p;
            }
            __syncthreads();
            float i1 = inv_g[((size_t)bh * 2 + 0) * Tn + r0 + 127];
            float i2 = inv_g[((size_t)bh * 2 + 1) * Tn + r0 + 127];
            ev = e_sh[0] * i1 - lam * (e_sh[1] * i2);
        }
        float4 z = make_float4(0.f, 0.f, 0.f, 0.f);
        #pragma unroll
        for (int i = 0; i < 8; ++i) {
            int f = i * 512 + t;               // 0..4095 float4s
            int row = f >> 5, c4 = (f & 31) << 2;
            float4 o = z;
            if (c == rt + 1 && f == 4064) o.x = ev;   // (row 127, col 0)
            *(float4*)&out[((size_t)bh * Tn + r0 + row) * Tn + cb + c4] = o;
        }
        return;
    }

    // ---------------- compute role ----------------
    if (t < 256) {
        int br = t >> 7, row = t & 127;
        inv_lds[br][row] = inv_g[((size_t)bh * 2 + br) * Tn + r0 + row];
    }

    int w = t >> 6, l = t & 63;
    int wr = (w & 3) * 32;          // wave row offset (local)
    int wc = (w >> 2) * 64;         // wave col offset (local)
    int lrow = l & 15, lk = l >> 4; // frag lane decomposition

    f32x4 acc[2][2][4];             // [branch][rf][cf]
    #pragma unroll
    for (int b = 0; b < 2; ++b)
        #pragma unroll
        for (int rf = 0; rf < 2; ++rf)
            #pragma unroll
            for (int cf = 0; cf < 4; ++cf)
                acc[b][rf][cf] = (f32x4){0.f, 0.f, 0.f, 0.f};

    const unsigned short* qh[2] = { qh1 + bb, qh2 + bb };
    const unsigned short* ql[2] = { ql1 + bb, ql2 + bb };
    const unsigned short* khp[2] = { kh1 + bb, kh2 + bb };
    const unsigned short* klp[2] = { kl1 + bb, kl2 + bb };

    // staging mapping: 512 threads x 32B = 16KB per pass
    int sc = t & 127;               // column
    int sg = (t >> 7) & 1;          // 0 = hi, 1 = lo
    int sq = t >> 8;                // which 32B half of the 64B k-slice

    #pragma unroll
    for (int pass = 0; pass < 4; ++pass) {
        const int b = pass >> 1, s = pass & 1;
        __syncthreads();            // WAR on Bhs/Bls
        {
            const unsigned short* srcp =
                (sg ? klp[b] : khp[b]) + (size_t)(cb + sc) * Dn + s * 32 + sq * 16;
            bf16x8 v0 = *(const bf16x8*)srcp;
            bf16x8 v1 = *(const bf16x8*)(srcp + 8);
            unsigned short* dstp = (sg ? Bls : Bhs) + sc * 40 + sq * 16;
            *(bf16x8*)dstp = v0;
            *(bf16x8*)(dstp + 8) = v1;
        }
        __syncthreads();
        // A fragments (global; row = lane&15, k = (lane>>4)*8 contiguous)
        const unsigned short* aqh = qh[b] + (size_t)(r0 + wr + lrow) * Dn + s * 32 + lk * 8;
        const unsigned short* aql = ql[b] + (size_t)(r0 + wr + lrow) * Dn + s * 32 + lk * 8;
        bf16x8 ah0 = *(const bf16x8*)aqh;
        bf16x8 ah1 = *(const bf16x8*)(aqh + 16 * Dn);
        bf16x8 al0 = *(const bf16x8*)aql;
        bf16x8 al1 = *(const bf16x8*)(aql + 16 * Dn);
        #pragma unroll
        for (int cf = 0; cf < 4; ++cf) {
            int col = wc + cf * 16 + lrow;
            bf16x8 bhf = *(const bf16x8*)&Bhs[col * 40 + lk * 8];
            bf16x8 blf = *(const bf16x8*)&Bls[col * 40 + lk * 8];
            acc[b][0][cf] = __builtin_amdgcn_mfma_f32_16x16x32_bf16(ah0, bhf, acc[b][0][cf], 0, 0, 0);
            acc[b][0][cf] = __builtin_amdgcn_mfma_f32_16x16x32_bf16(ah0, blf, acc[b][0][cf], 0, 0, 0);
            acc[b][0][cf] = __builtin_amdgcn_mfma_f32_16x16x32_bf16(al0, bhf, acc[b][0][cf], 0, 0, 0);
            acc[b][1][cf] = __builtin_amdgcn_mfma_f32_16x16x32_bf16(ah1, bhf, acc[b][1][cf], 0, 0, 0);
            acc[b][1][cf] = __builtin_amdgcn_mfma_f32_16x16x32_bf16(ah1, blf, acc[b][1][cf], 0, 0, 0);
            acc[b][1][cf] = __builtin_amdgcn_mfma_f32_16x16x32_bf16(al1, bhf, acc[b][1][cf], 0, 0, 0);
        }
    }

    // ---------------- epilogue: LDS-staged coalesced writes ----------------
    // D layout: col = lane&15 (+cf*16+wc), row = lk*4 + reg (+rf*16+wr).
    int ws_sel = w & 3;             // which stripe this wave's rows live in
    #pragma unroll
    for (int s = 0; s < 4; ++s) {
        __syncthreads();            // compute done / previous stripe reads done
        if (ws_sel == s) {
            #pragma unroll
            for (int rf = 0; rf < 2; ++rf) {
                #pragma unroll
                for (int rg = 0; rg < 4; ++rg) {
                    int srow = rf * 16 + lk * 4 + rg;     // 0..31 within stripe
                    int lr = s * 32 + srow;               // 0..127 within tile
                    int grow = r0 + lr;
                    float i1 = inv_lds[0][lr], i2 = inv_lds[1][lr];
                    #pragma unroll
                    for (int cf = 0; cf < 4; ++cf) {
                        int lcol = wc + cf * 16 + lrow;
                        float v1 = acc[0][rf][cf][rg];
                        float v2 = acc[1][rf][cf][rg];
                        if (c == rt && cb + lcol > grow + 1) { v1 = 0.f; v2 = 0.f; }
                        Cst[srow][lcol] = v1 * i1 - lam * (v2 * i2);
                    }
                }
            }
        }
        __syncthreads();
        #pragma unroll
        for (int p = 0; p < 2; ++p) {
            int f = p * 512 + t;            // 0..1023 float4s
            int row = f >> 5, c4 = (f & 31) << 2;
            float4 o = *(const float4*)&Cst[row][c4];
            *(float4*)&out[((size_t)bh * Tn + r0 + s * 32 + row) * Tn + cb + c4] = o;
        }
    }
}

// ---------------------------------------------------------------------------
extern "C" void kernel_launch(void* const* d_in, const int* in_sizes, int n_in,
                              void* d_out, int out_size, void* d_ws, size_t ws_size,
                              hipStream_t stream) {
    const float* q   = (const float*)d_in[0];
    const float* k   = (const float*)d_in[1];
    const float* W1q = (const float*)d_in[2];
    const float* W1k = (const float*)d_in[3];
    const float* W2q = (const float*)d_in[4];
    const float* W2k = (const float*)d_in[5];
    const float* lq1 = (const float*)d_in[6];
    const float* lk1 = (const float*)d_in[7];
    const float* lq2 = (const float*)d_in[8];
    const float* lk2 = (const float*)d_in[9];
    float* out = (float*)d_out;
    float* ws  = (float*)d_ws;

    float* qf1 = ws;
    float* kf1 = ws + (size_t)N4;
    float* qf2 = ws + 2 * (size_t)N4;
    float* kf2 = ws + 3 * (size_t)N4;
    unsigned short* us = (unsigned short*)(ws + 4 * (size_t)N4);
    unsigned short* qh1 = us;
    unsigned short* ql1 = us + 1 * (size_t)N4;
    unsigned short* kh1 = us + 2 * (size_t)N4;
    unsigned short* kl1 = us + 3 * (size_t)N4;
    unsigned short* qh2 = us + 4 * (size_t)N4;
    unsigned short* ql2 = us + 5 * (size_t)N4;
    unsigned short* kh2 = us + 6 * (size_t)N4;
    unsigned short* kl2 = us + 7 * (size_t)N4;
    float* bs  = ws + 8 * (size_t)N4;          // 8 ushort tensors == 4*N4 floats
    float* kc  = bs + 65536;
    float* lamp = kc + 65536;
    float* inv_s = lamp + 64;                  // 64*2*1024 floats

    k_lambda<<<1, 64, 0, stream>>>(lq1, lk1, lq2, lk2, lamp);
    k_proj4<<<4096, 256, 0, stream>>>(q, k, W1q, W1k, W2q, W2k,
                                      qf1, kf1, qf2, kf2,
                                      qh1, ql1, kh1, kl1, qh2, ql2, kh2, kl2);
    k_blocksum<<<1024, 256, 0, stream>>>(kf1, kf2, bs);
    k_prefix<<<128, 64, 0, stream>>>(bs, kc);
    k_s2<<<1024, 256, 0, stream>>>(qf1, kf1, qf2, kf2, kc, inv_s);
    k_tile<<<4096, 512, 0, stream>>>(qh1, ql1, qh2, ql2, kh1, kl1, kh2, kl2,
                                     qf1, qf2, kf1, kf2, inv_s, lamp, out);
}